// Round 16
// baseline (955.008 us; speedup 1.0000x reference)
//
#include <hip/hip_runtime.h>
#include <stdint.h>

typedef unsigned short u16;
typedef unsigned int   u32;

using bf16x8 = __attribute__((ext_vector_type(8))) __bf16;
using f32x4  = __attribute__((ext_vector_type(4))) float;
using f32x16 = __attribute__((ext_vector_type(16))) float;

#define GAS(p) ((const __attribute__((address_space(1))) void*)(p))
#define LAS(p) ((__attribute__((address_space(3))) void*)(p))

__device__ __forceinline__ u16 f2bf(float f) {
  union { float f; u32 u; } v; v.f = f;
  return (u16)((v.u + 0x7FFFu + ((v.u >> 16) & 1u)) >> 16);
}

__device__ __forceinline__ u32 cvtpk(float lo, float hi) {
  u32 r;
  asm("v_cvt_pk_bf16_f32 %0, %1, %2" : "=v"(r) : "v"(lo), "v"(hi));
  return r;
}

// vdst lanes [32:63] <-> vsrc lanes [0:31].  Only call with DISTINCT values
// (identical values get register-coalesced -> self-swap bug).
__device__ __forceinline__ void perm32swap(u32& a, u32& b) {
  asm volatile("v_permlane32_swap_b32 %0, %1" : "+v"(a), "+v"(b));
}

// ---------------- cast x -> bf16 (linear only; conv gathers from xb) -------
__global__ __launch_bounds__(256) void k_cast_x(const float* __restrict__ x,
    u16* __restrict__ xb) {
  int t   = blockIdx.x * 256 + threadIdx.x;   // 2,097,152 total
  int row = t >> 6;
  int seg = t & 63;
  const float* src = x + (size_t)row * 512 + seg * 8;
  float4 a = *(const float4*)src;
  float4 b = *(const float4*)(src + 4);
  uint4 pk;
  pk.x = (u32)f2bf(a.x) | ((u32)f2bf(a.y) << 16);
  pk.y = (u32)f2bf(a.z) | ((u32)f2bf(a.w) << 16);
  pk.z = (u32)f2bf(b.x) | ((u32)f2bf(b.y) << 16);
  pk.w = (u32)f2bf(b.z) | ((u32)f2bf(b.w) << 16);
  *(uint4*)(xb + (size_t)row * 512 + seg * 8) = pk;
}

// ---------------- weights -> bf16 (+ sr_w repack OIHW -> [O][ky,kx,I]) -----
__global__ __launch_bounds__(256) void k_cast_w(const float* __restrict__ qw,
    const float* __restrict__ kvw, const float* __restrict__ pw,
    const float* __restrict__ srw, u16* __restrict__ oqw, u16* __restrict__ okvw,
    u16* __restrict__ opw, u16* __restrict__ osrw) {
  int t = blockIdx.x * 256 + threadIdx.x;     // 2,097,152 total
  if (t < 262144) {
    oqw[t] = f2bf(qw[t]);
  } else if (t < 786432) {
    int i = t - 262144; okvw[i] = f2bf(kvw[i]);
  } else if (t < 1048576) {
    int i = t - 786432; opw[i] = f2bf(pw[i]);
  } else {
    int i = t - 1048576;            // dst index: o*2048 + kk*512 + ic
    int o  = i >> 11;
    int r  = i & 2047;
    int kk = r >> 9;                // ky*2+kx
    int ic = r & 511;
    int ky = kk >> 1, kx = kk & 1;
    osrw[i] = f2bf(srw[(((size_t)o * 512 + ic) * 2 + ky) * 2 + kx]);
  }
}

// ---------------- conv GEMM 128x128, A gathered straight from xb -----------
// Patch row r: b=r>>10, py=(r&1023)>>5, px=r&31.  Patch col kcol=kk*512+ic
// maps to xb[(b*4096 + (2py+ky)*64 + 2px+kx)*512 + ic], kk=ky*2+kx.
// Per-lane base covers (b,py,px,ks); the kk/ic part is a UNIFORM offset:
//   off(k0) = ((k0>>10)&1)*32768 + ((k0>>9)&1)*512 + (k0&511).
__global__ __launch_bounds__(256) void k_gemm_conv(const u16* __restrict__ xb,
    const u16* __restrict__ B, float* __restrict__ C, int N, int K) {
  __shared__ u16 lA[2][128 * 32];
  __shared__ u16 lB[2][128 * 32];
  const int tid  = threadIdx.x;
  const int wid  = tid >> 6;
  const int lane = tid & 63;
  const int brow = blockIdx.x * 128;
  const int bcol = blockIdx.y * 128;
  const int wr = (wid >> 1) * 64;
  const int wc = (wid & 1) * 64;

  const int c0 = wid * 2, c1 = c0 + 1;
  const int rl = lane >> 2;
  const int ks = (lane & 3) * 8;
  auto abase = [&](int r) {
    int b2 = r >> 10, pr = r & 1023;
    return xb + ((size_t)b2 * 4096 + (pr >> 5) * 128 + (pr & 31) * 2) * 512 + ks;
  };
  const u16* gA0 = abase(brow + c0 * 16 + rl);
  const u16* gA1 = abase(brow + c1 * 16 + rl);
  const u16* gB0 = B + (size_t)(bcol + c0 * 16 + rl) * K + ks;
  const u16* gB1 = B + (size_t)(bcol + c1 * 16 + rl) * K + ks;

  f32x4 acc[4][4] = {};
  const int ar = lane & 15;
  const int ak = (lane >> 4) * 8;

  auto stage = [&](int k0, int buf) {
    int off = ((k0 >> 10) & 1) * 32768 + ((k0 >> 9) & 1) * 512 + (k0 & 511);
    __builtin_amdgcn_global_load_lds(GAS(gA0 + off), LAS(&lA[buf][c0 * 512]), 16, 0, 0);
    __builtin_amdgcn_global_load_lds(GAS(gA1 + off), LAS(&lA[buf][c1 * 512]), 16, 0, 0);
    __builtin_amdgcn_global_load_lds(GAS(gB0 + k0),  LAS(&lB[buf][c0 * 512]), 16, 0, 0);
    __builtin_amdgcn_global_load_lds(GAS(gB1 + k0),  LAS(&lB[buf][c1 * 512]), 16, 0, 0);
  };

  stage(0, 0);
  __syncthreads();

  const int nk = K >> 5;
  for (int t = 0; t < nk; ++t) {
    const int buf = t & 1;
    if (t + 1 < nk) stage((t + 1) << 5, buf ^ 1);
    bf16x8 af[4], bfr[4];
#pragma unroll
    for (int m = 0; m < 4; ++m)
      af[m] = *(const bf16x8*)&lA[buf][(wr + m * 16 + ar) * 32 + ak];
#pragma unroll
    for (int n = 0; n < 4; ++n)
      bfr[n] = *(const bf16x8*)&lB[buf][(wc + n * 16 + ar) * 32 + ak];
#pragma unroll
    for (int m = 0; m < 4; ++m)
#pragma unroll
      for (int n = 0; n < 4; ++n)
        acc[m][n] = __builtin_amdgcn_mfma_f32_16x16x32_bf16(af[m], bfr[n], acc[m][n], 0, 0, 0);
    __syncthreads();
  }

  const int crow = brow + wr + (lane >> 4) * 4;
  const int ccol = bcol + wc + (lane & 15);
#pragma unroll
  for (int n = 0; n < 4; ++n) {
    int col = ccol + n * 16;
#pragma unroll
    for (int m = 0; m < 4; ++m)
#pragma unroll
      for (int r = 0; r < 4; ++r)
        C[(size_t)(crow + m * 16 + r) * N + col] = acc[m][n][r];
  }
}

// ---------------- GEMM 256x128, 8 waves (4M x 2N), BK=32, 2-phase dbuf -----
template<bool OUT_BF16, bool ADD_BIAS>
__global__ __launch_bounds__(512) void k_gemm_bt2(const u16* __restrict__ A,
    const u16* __restrict__ B, void* __restrict__ Cv,
    const float* __restrict__ bias, float scale, int M, int N, int K) {
  __shared__ u16 lA[2][256 * 32];   // 16KB per buf
  __shared__ u16 lB[2][128 * 32];   // 8KB per buf
  const int tid  = threadIdx.x;
  const int wid  = tid >> 6;        // 0..7
  const int lane = tid & 63;
  const int brow = blockIdx.x * 256;
  const int bcol = blockIdx.y * 128;
  const int wr = (wid >> 1) * 64;   // 4 M-groups
  const int wc = (wid & 1) * 64;    // 2 N-groups

  const int rl = lane >> 2;          // row within 16-row group
  const int ks = (lane & 3) * 8;     // 8-elem k chunk
  const u16* gA0 = A + (size_t)(brow + wid * 16 + rl) * K + ks;
  const u16* gA1 = A + (size_t)(brow + 128 + wid * 16 + rl) * K + ks;
  const u16* gB0 = B + (size_t)(bcol + wid * 16 + rl) * K + ks;

  f32x4 acc[4][4] = {};
  const int ar = lane & 15;
  const int ak = (lane >> 4) * 8;

  auto stage = [&](int k0, int buf) {
    __builtin_amdgcn_global_load_lds(GAS(gA0 + k0), LAS(&lA[buf][wid * 512]), 16, 0, 0);
    __builtin_amdgcn_global_load_lds(GAS(gA1 + k0), LAS(&lA[buf][4096 + wid * 512]), 16, 0, 0);
    __builtin_amdgcn_global_load_lds(GAS(gB0 + k0), LAS(&lB[buf][wid * 512]), 16, 0, 0);
  };

  stage(0, 0);
  __syncthreads();

  const int nk = K >> 5;
  for (int t = 0; t < nk; ++t) {
    const int buf = t & 1;
    if (t + 1 < nk) stage((t + 1) << 5, buf ^ 1);
    bf16x8 af[4], bfr[4];
#pragma unroll
    for (int m = 0; m < 4; ++m)
      af[m] = *(const bf16x8*)&lA[buf][(wr + m * 16 + ar) * 32 + ak];
#pragma unroll
    for (int n = 0; n < 4; ++n)
      bfr[n] = *(const bf16x8*)&lB[buf][(wc + n * 16 + ar) * 32 + ak];
#pragma unroll
    for (int m = 0; m < 4; ++m)
#pragma unroll
      for (int n = 0; n < 4; ++n)
        acc[m][n] = __builtin_amdgcn_mfma_f32_16x16x32_bf16(af[m], bfr[n], acc[m][n], 0, 0, 0);
    __syncthreads();
  }

  const int crow = brow + wr + (lane >> 4) * 4;
  const int ccol = bcol + wc + (lane & 15);
#pragma unroll
  for (int n = 0; n < 4; ++n) {
    int col = ccol + n * 16;
    float bv = ADD_BIAS ? bias[col] : 0.0f;
#pragma unroll
    for (int m = 0; m < 4; ++m)
#pragma unroll
      for (int r = 0; r < 4; ++r) {
        size_t idx = (size_t)(crow + m * 16 + r) * N + col;
        float val = acc[m][n][r] * scale + bv;
        if (OUT_BF16) ((u16*)Cv)[idx] = f2bf(val);
        else          ((float*)Cv)[idx] = val;
      }
  }
}

// ---------------- kv GEMM 256x128 with fused pack epilogue -----------------
// Same body as k_gemm_bt2 (M=8192, N=1024, K=512); epilogue writes straight
// into the packed K / V^T tile layouts (deletes k_pack + kvb round-trip).
__global__ __launch_bounds__(512) void k_gemm_kv(const u16* __restrict__ A,
    const u16* __restrict__ B, u16* __restrict__ kpk, u16* __restrict__ vpk) {
  const int K = 512;
  __shared__ u16 lA[2][256 * 32];
  __shared__ u16 lB[2][128 * 32];
  const int tid  = threadIdx.x;
  const int wid  = tid >> 6;
  const int lane = tid & 63;
  const int brow = blockIdx.x * 256;
  const int bcol = blockIdx.y * 128;
  const int wr = (wid >> 1) * 64;
  const int wc = (wid & 1) * 64;

  const int rl = lane >> 2;
  const int ks = (lane & 3) * 8;
  const u16* gA0 = A + (size_t)(brow + wid * 16 + rl) * K + ks;
  const u16* gA1 = A + (size_t)(brow + 128 + wid * 16 + rl) * K + ks;
  const u16* gB0 = B + (size_t)(bcol + wid * 16 + rl) * K + ks;

  f32x4 acc[4][4] = {};
  const int ar = lane & 15;
  const int ak = (lane >> 4) * 8;

  auto stage = [&](int k0, int buf) {
    __builtin_amdgcn_global_load_lds(GAS(gA0 + k0), LAS(&lA[buf][wid * 512]), 16, 0, 0);
    __builtin_amdgcn_global_load_lds(GAS(gA1 + k0), LAS(&lA[buf][4096 + wid * 512]), 16, 0, 0);
    __builtin_amdgcn_global_load_lds(GAS(gB0 + k0), LAS(&lB[buf][wid * 512]), 16, 0, 0);
  };

  stage(0, 0);
  __syncthreads();

  const int nk = K >> 5;
  for (int t = 0; t < nk; ++t) {
    const int buf = t & 1;
    if (t + 1 < nk) stage((t + 1) << 5, buf ^ 1);
    bf16x8 af[4], bfr[4];
#pragma unroll
    for (int m = 0; m < 4; ++m)
      af[m] = *(const bf16x8*)&lA[buf][(wr + m * 16 + ar) * 32 + ak];
#pragma unroll
    for (int n = 0; n < 4; ++n)
      bfr[n] = *(const bf16x8*)&lB[buf][(wc + n * 16 + ar) * 32 + ak];
#pragma unroll
    for (int m = 0; m < 4; ++m)
#pragma unroll
      for (int n = 0; n < 4; ++n)
        acc[m][n] = __builtin_amdgcn_mfma_f32_16x16x32_bf16(af[m], bfr[n], acc[m][n], 0, 0, 0);
    __syncthreads();
  }

  const int crow = brow + wr + (lane >> 4) * 4;
  const int ccol = bcol + wc + (lane & 15);
  const bool isV = (bcol >= 512);
  u16* dst = isV ? vpk : kpk;

  int colt[4];
#pragma unroll
  for (int n = 0; n < 4; ++n) {
    int col = ccol + n * 16;
    int rem = col & 511;
    int m = rem >> 6, c = rem & 63;
    colt[n] = isV ? (m * 65536 + (c >> 5) * 2048 + (c & 31) * 8)
                  : (m * 65536 + (c >> 4) * 512 + ((c >> 3) & 1) * 256 + (c & 7));
  }
#pragma unroll
  for (int mi = 0; mi < 4; ++mi)
#pragma unroll
    for (int r = 0; r < 4; ++r) {
      int row = crow + mi * 16 + r;
      int b2 = row >> 10, d = row & 1023;
      int kt = d >> 6, dl = d & 63;
      int rowt = b2 * 524288 + kt * 4096 +
                 (isV ? ((dl >> 4) * 512 + ((dl >> 3) & 1) * 256 + (dl & 7))
                      : ((dl >> 5) * 2048 + (dl & 31) * 8));
#pragma unroll
      for (int n = 0; n < 4; ++n)
        dst[rowt + colt[n]] = f2bf(acc[mi][n][r]);
    }
}

// ---------------- LayerNorm (adds sr_b first), rows of 512, wave/row -------
__global__ __launch_bounds__(256) void k_ln(const float* __restrict__ cin,
    const float* __restrict__ srb, const float* __restrict__ g,
    const float* __restrict__ bb, u16* __restrict__ out) {
  int row  = blockIdx.x * 4 + (threadIdx.x >> 6);
  int lane = threadIdx.x & 63;
  const float* src = cin + (size_t)row * 512 + lane * 8;
  float4 a  = *(const float4*)src;
  float4 b  = *(const float4*)(src + 4);
  float4 s1 = *(const float4*)(srb + lane * 8);
  float4 s2 = *(const float4*)(srb + lane * 8 + 4);
  float v[8] = { a.x + s1.x, a.y + s1.y, a.z + s1.z, a.w + s1.w,
                 b.x + s2.x, b.y + s2.y, b.z + s2.z, b.w + s2.w };
  float sum = 0.f, sq = 0.f;
#pragma unroll
  for (int i = 0; i < 8; ++i) { sum += v[i]; sq += v[i] * v[i]; }
  for (int m = 1; m < 64; m <<= 1) {
    sum += __shfl_xor(sum, m, 64);
    sq  += __shfl_xor(sq,  m, 64);
  }
  float mean = sum * (1.0f / 512.0f);
  float var  = sq * (1.0f / 512.0f) - mean * mean;
  float rstd = rsqrtf(var + 1e-5f);
  float4 g1 = *(const float4*)(g + lane * 8);
  float4 g2 = *(const float4*)(g + lane * 8 + 4);
  float4 b1 = *(const float4*)(bb + lane * 8);
  float4 b2 = *(const float4*)(bb + lane * 8 + 4);
  float gg[8] = { g1.x, g1.y, g1.z, g1.w, g2.x, g2.y, g2.z, g2.w };
  float bv[8] = { b1.x, b1.y, b1.z, b1.w, b2.x, b2.y, b2.z, b2.w };
  uint4 pk;
  u32 w0[8];
#pragma unroll
  for (int i = 0; i < 8; ++i) w0[i] = f2bf((v[i] - mean) * rstd * gg[i] + bv[i]);
  pk.x = w0[0] | (w0[1] << 16);
  pk.y = w0[2] | (w0[3] << 16);
  pk.z = w0[4] | (w0[5] << 16);
  pk.w = w0[6] | (w0[7] << 16);
  *(uint4*)(out + (size_t)row * 512 + lane * 8) = pk;
}

// ---------------- flash attention (r15 structure, 5 waves/SIMD target) -----
// Swapped 32x32, no-max softmax (p = exp2(z)); K double-buffered in LDS via
// global_load_lds; V read straight from packed global (L2-resident); row-sum
// on the MFMA pipe via ones A-operand. __launch_bounds__(256,5) caps VGPR at
// 102 -> 5 waves/SIMD (was 108 -> 4). If FETCH rises (spill), revert.
__global__ __launch_bounds__(256, 5) void k_attn(const u16* __restrict__ q,
    const u16* __restrict__ kpk, const u16* __restrict__ vpk,
    u16* __restrict__ out) {
  __shared__ u16 kl[2][4096];   // 8KB per buffer, K only
  const int sw   = blockIdx.x;               // 0..2047
  const int slot = sw >> 3;
  const int bm   = (sw & 7) * 8 + (slot >> 5);
  const int qx   = slot & 31;
  const int b  = bm >> 3, mm = bm & 7;
  const int wid  = threadIdx.x >> 6;
  const int lane = threadIdx.x & 63;
  const int l31  = lane & 31;
  const int hi   = lane >> 5;
  const int hi8  = hi * 8;
  const int q0   = qx * 128 + wid * 32;

  const u16* qrow = q + (size_t)(b * 4096 + q0 + l31) * 512 + mm * 64 + hi8;
  bf16x8 qf[4];
#pragma unroll
  for (int cs = 0; cs < 4; ++cs) qf[cs] = *(const bf16x8*)(qrow + cs * 16);

  const u16* kp = kpk + (size_t)bm * 65536;
  const u16* vp = vpk + (size_t)bm * 65536;
  const int loff = lane * 8;
  const int c0   = wid * 2;

  union { u32 w[4]; bf16x8 v; } onesu;
  onesu.w[0] = onesu.w[1] = onesu.w[2] = onesu.w[3] = 0x3F803F80u;
  const bf16x8 ones = onesu.v;

  f32x16 o0 = {}, o1 = {}, o2 = {};

  auto stage = [&](int t, int buf) {
    const u16* ks = kp + t * 4096 + c0 * 512 + loff;
    __builtin_amdgcn_global_load_lds(GAS(ks),       LAS(&kl[buf][c0 * 512]),       16, 0, 0);
    __builtin_amdgcn_global_load_lds(GAS(ks + 512), LAS(&kl[buf][c0 * 512 + 512]), 16, 0, 0);
  };

  auto body = [&](int t, int buf) {
    if (t + 1 < 16) stage(t + 1, buf ^ 1);

    const u16* vt = vp + t * 4096 + loff;
    bf16x8 vf[8];
#pragma unroll
    for (int i = 0; i < 8; ++i) vf[i] = *(const bf16x8*)(vt + i * 512);

    bf16x8 kf[8];
#pragma unroll
    for (int i = 0; i < 8; ++i)
      kf[i] = *(const bf16x8*)&kl[buf][i * 512 + loff];

    f32x16 s0 = {}, s1 = {};
    __builtin_amdgcn_s_setprio(1);
#pragma unroll
    for (int cs = 0; cs < 4; ++cs) {
      s0 = __builtin_amdgcn_mfma_f32_32x32x16_bf16(kf[cs],     qf[cs], s0, 0, 0, 0);
      s1 = __builtin_amdgcn_mfma_f32_32x32x16_bf16(kf[4 + cs], qf[cs], s1, 0, 0, 0);
    }
    __builtin_amdgcn_s_setprio(0);

    float pr[2][16];
#pragma unroll
    for (int i = 0; i < 16; ++i) {
      pr[0][i] = __builtin_amdgcn_exp2f(s0[i]);
      pr[1][i] = __builtin_amdgcn_exp2f(s1[i]);
    }

    bf16x8 pa[4];
#pragma unroll
    for (int half = 0; half < 2; ++half)
#pragma unroll
      for (int ks = 0; ks < 2; ++ks) {
        u32 wa = cvtpk(pr[half][ks * 8 + 0], pr[half][ks * 8 + 1]);
        u32 wb = cvtpk(pr[half][ks * 8 + 4], pr[half][ks * 8 + 5]);
        u32 wc = cvtpk(pr[half][ks * 8 + 2], pr[half][ks * 8 + 3]);
        u32 wd = cvtpk(pr[half][ks * 8 + 6], pr[half][ks * 8 + 7]);
        perm32swap(wa, wb);
        perm32swap(wc, wd);
        union { u32 w[4]; bf16x8 v; } uu;
        uu.w[0] = wa; uu.w[1] = wc; uu.w[2] = wb; uu.w[3] = wd;
        pa[half * 2 + ks] = uu.v;
      }

    __builtin_amdgcn_s_setprio(1);
#pragma unroll
    for (int ks = 0; ks < 4; ++ks) {
      o0 = __builtin_amdgcn_mfma_f32_32x32x16_bf16(vf[ks],     pa[ks], o0, 0, 0, 0);
      o1 = __builtin_amdgcn_mfma_f32_32x32x16_bf16(vf[4 + ks], pa[ks], o1, 0, 0, 0);
      o2 = __builtin_amdgcn_mfma_f32_32x32x16_bf16(ones,       pa[ks], o2, 0, 0, 0);
    }
    __builtin_amdgcn_s_setprio(0);
    __syncthreads();
  };

  stage(0, 0);
  __syncthreads();
  for (int t = 0; t < 16; t += 2) {
    body(t, 0);
    body(t + 1, 1);
  }

  float inv = 1.0f / o2[0];
  u16* obase = out + (size_t)(b * 4096 + q0 + l31) * 512 + mm * 64 + hi * 4;
#pragma unroll
  for (int ct = 0; ct < 2; ++ct)
#pragma unroll
    for (int g = 0; g < 4; ++g) {
      ushort4 st;
      st.x = f2bf((ct ? o1[g * 4 + 0] : o0[g * 4 + 0]) * inv);
      st.y = f2bf((ct ? o1[g * 4 + 1] : o0[g * 4 + 1]) * inv);
      st.z = f2bf((ct ? o1[g * 4 + 2] : o0[g * 4 + 2]) * inv);
      st.w = f2bf((ct ? o1[g * 4 + 3] : o0[g * 4 + 3]) * inv);
      *(ushort4*)(obase + ct * 32 + g * 8) = st;
    }
}

// ---------------------------------------------------------------------------
extern "C" void kernel_launch(void* const* d_in, const int* in_sizes, int n_in,
                              void* d_out, int out_size, void* d_ws, size_t ws_size,
                              hipStream_t stream) {
  const float* x      = (const float*)d_in[0];
  const float* q_w    = (const float*)d_in[3];
  const float* kv_w   = (const float*)d_in[4];
  const float* proj_w = (const float*)d_in[5];
  const float* proj_b = (const float*)d_in[6];
  const float* sr_w   = (const float*)d_in[7];
  const float* sr_b   = (const float*)d_in[8];
  const float* ng     = (const float*)d_in[9];
  const float* nb     = (const float*)d_in[10];

  char* ws = (char*)d_ws;
  size_t off = 0;
  auto alloc = [&](size_t bytes) {
    char* p = ws + off;
    off += (bytes + 255) & ~(size_t)255;
    return p;
  };
  u16* wq      = (u16*)alloc(512 * 512 * 2);
  u16* wkv     = (u16*)alloc(1024 * 512 * 2);
  u16* wpr     = (u16*)alloc(512 * 512 * 2);
  u16* wsr     = (u16*)alloc(512 * 2048 * 2);
  u16* xb      = (u16*)alloc(33554432);      // [32768,512] bf16
  u16* qbuf    = (u16*)alloc(33554432);      // [32768,512] bf16 (pre-scaled)
  u16* xsln    = (u16*)alloc(8388608);       // [8192,512]  bf16
  u16* kpkb    = (u16*)alloc(8388608);       // packed K tiles
  u16* vpkb    = (u16*)alloc(8388608);       // packed V^T tiles
  float* convout = (float*)alloc(16777216);  // [8192,512] f32
  u16* attn_o  = xb;                         // alias: xb dead after conv GEMM

  const float zsc = 0.125f * 1.44269504f;    // SCALE * log2(e)

  k_cast_x<<<8192, 256, 0, stream>>>(x, xb);
  k_cast_w<<<8192, 256, 0, stream>>>(q_w, kv_w, proj_w, sr_w, wq, wkv, wpr, wsr);
  k_gemm_bt2<true,  false><<<dim3(128, 4), 512, 0, stream>>>(xb, wq, qbuf, nullptr, zsc, 32768, 512, 512);
  k_gemm_conv<<<dim3(64, 4), 256, 0, stream>>>(xb, wsr, convout, 512, 2048);
  k_ln<<<2048, 256, 0, stream>>>(convout, sr_b, ng, nb, xsln);
  k_gemm_kv<<<dim3(32, 8), 512, 0, stream>>>(xsln, wkv, kpkb, vpkb);
  k_attn<<<2048, 256, 0, stream>>>(qbuf, kpkb, vpkb, attn_o);
  k_gemm_bt2<false, true><<<dim3(128, 4), 512, 0, stream>>>(attn_o, wpr, (float*)d_out, proj_b, 1.0f, 32768, 512, 512);
}

// Round 17
// 239.417 us; speedup vs baseline: 3.9889x; 3.9889x over previous
//
#include <hip/hip_runtime.h>
#include <stdint.h>

typedef unsigned short u16;
typedef unsigned int   u32;

using bf16x8 = __attribute__((ext_vector_type(8))) __bf16;
using f32x4  = __attribute__((ext_vector_type(4))) float;
using f32x16 = __attribute__((ext_vector_type(16))) float;

#define GAS(p) ((const __attribute__((address_space(1))) void*)(p))
#define LAS(p) ((__attribute__((address_space(3))) void*)(p))

__device__ __forceinline__ u16 f2bf(float f) {
  union { float f; u32 u; } v; v.f = f;
  return (u16)((v.u + 0x7FFFu + ((v.u >> 16) & 1u)) >> 16);
}

__device__ __forceinline__ u32 cvtpk(float lo, float hi) {
  u32 r;
  asm("v_cvt_pk_bf16_f32 %0, %1, %2" : "=v"(r) : "v"(lo), "v"(hi));
  return r;
}

// vdst lanes [32:63] <-> vsrc lanes [0:31].  Only call with DISTINCT values
// (identical values get register-coalesced -> self-swap bug).
__device__ __forceinline__ void perm32swap(u32& a, u32& b) {
  asm volatile("v_permlane32_swap_b32 %0, %1" : "+v"(a), "+v"(b));
}

// ---------------- cast x -> bf16 (linear only; conv gathers from xb) -------
__global__ __launch_bounds__(256) void k_cast_x(const float* __restrict__ x,
    u16* __restrict__ xb) {
  int t   = blockIdx.x * 256 + threadIdx.x;   // 2,097,152 total
  int row = t >> 6;
  int seg = t & 63;
  const float* src = x + (size_t)row * 512 + seg * 8;
  float4 a = *(const float4*)src;
  float4 b = *(const float4*)(src + 4);
  uint4 pk;
  pk.x = (u32)f2bf(a.x) | ((u32)f2bf(a.y) << 16);
  pk.y = (u32)f2bf(a.z) | ((u32)f2bf(a.w) << 16);
  pk.z = (u32)f2bf(b.x) | ((u32)f2bf(b.y) << 16);
  pk.w = (u32)f2bf(b.z) | ((u32)f2bf(b.w) << 16);
  *(uint4*)(xb + (size_t)row * 512 + seg * 8) = pk;
}

// ---------------- weights -> bf16 (+ sr_w repack OIHW -> [O][ky,kx,I]) -----
__global__ __launch_bounds__(256) void k_cast_w(const float* __restrict__ qw,
    const float* __restrict__ kvw, const float* __restrict__ pw,
    const float* __restrict__ srw, u16* __restrict__ oqw, u16* __restrict__ okvw,
    u16* __restrict__ opw, u16* __restrict__ osrw) {
  int t = blockIdx.x * 256 + threadIdx.x;     // 2,097,152 total
  if (t < 262144) {
    oqw[t] = f2bf(qw[t]);
  } else if (t < 786432) {
    int i = t - 262144; okvw[i] = f2bf(kvw[i]);
  } else if (t < 1048576) {
    int i = t - 786432; opw[i] = f2bf(pw[i]);
  } else {
    int i = t - 1048576;            // dst index: o*2048 + kk*512 + ic
    int o  = i >> 11;
    int r  = i & 2047;
    int kk = r >> 9;                // ky*2+kx
    int ic = r & 511;
    int ky = kk >> 1, kx = kk & 1;
    osrw[i] = f2bf(srw[(((size_t)o * 512 + ic) * 2 + ky) * 2 + kx]);
  }
}

// ---------------- conv GEMM 128x128, A gathered straight from xb -----------
// Patch row r: b=r>>10, py=(r&1023)>>5, px=r&31.  Patch col kcol=kk*512+ic
// maps to xb[(b*4096 + (2py+ky)*64 + 2px+kx)*512 + ic], kk=ky*2+kx.
// Per-lane base covers (b,py,px,ks); the kk/ic part is a UNIFORM offset:
//   off(k0) = ((k0>>10)&1)*32768 + ((k0>>9)&1)*512 + (k0&511).
__global__ __launch_bounds__(256) void k_gemm_conv(const u16* __restrict__ xb,
    const u16* __restrict__ B, float* __restrict__ C, int N, int K) {
  __shared__ u16 lA[2][128 * 32];
  __shared__ u16 lB[2][128 * 32];
  const int tid  = threadIdx.x;
  const int wid  = tid >> 6;
  const int lane = tid & 63;
  const int brow = blockIdx.x * 128;
  const int bcol = blockIdx.y * 128;
  const int wr = (wid >> 1) * 64;
  const int wc = (wid & 1) * 64;

  const int c0 = wid * 2, c1 = c0 + 1;
  const int rl = lane >> 2;
  const int ks = (lane & 3) * 8;
  auto abase = [&](int r) {
    int b2 = r >> 10, pr = r & 1023;
    return xb + ((size_t)b2 * 4096 + (pr >> 5) * 128 + (pr & 31) * 2) * 512 + ks;
  };
  const u16* gA0 = abase(brow + c0 * 16 + rl);
  const u16* gA1 = abase(brow + c1 * 16 + rl);
  const u16* gB0 = B + (size_t)(bcol + c0 * 16 + rl) * K + ks;
  const u16* gB1 = B + (size_t)(bcol + c1 * 16 + rl) * K + ks;

  f32x4 acc[4][4] = {};
  const int ar = lane & 15;
  const int ak = (lane >> 4) * 8;

  auto stage = [&](int k0, int buf) {
    int off = ((k0 >> 10) & 1) * 32768 + ((k0 >> 9) & 1) * 512 + (k0 & 511);
    __builtin_amdgcn_global_load_lds(GAS(gA0 + off), LAS(&lA[buf][c0 * 512]), 16, 0, 0);
    __builtin_amdgcn_global_load_lds(GAS(gA1 + off), LAS(&lA[buf][c1 * 512]), 16, 0, 0);
    __builtin_amdgcn_global_load_lds(GAS(gB0 + k0),  LAS(&lB[buf][c0 * 512]), 16, 0, 0);
    __builtin_amdgcn_global_load_lds(GAS(gB1 + k0),  LAS(&lB[buf][c1 * 512]), 16, 0, 0);
  };

  stage(0, 0);
  __syncthreads();

  const int nk = K >> 5;
  for (int t = 0; t < nk; ++t) {
    const int buf = t & 1;
    if (t + 1 < nk) stage((t + 1) << 5, buf ^ 1);
    bf16x8 af[4], bfr[4];
#pragma unroll
    for (int m = 0; m < 4; ++m)
      af[m] = *(const bf16x8*)&lA[buf][(wr + m * 16 + ar) * 32 + ak];
#pragma unroll
    for (int n = 0; n < 4; ++n)
      bfr[n] = *(const bf16x8*)&lB[buf][(wc + n * 16 + ar) * 32 + ak];
#pragma unroll
    for (int m = 0; m < 4; ++m)
#pragma unroll
      for (int n = 0; n < 4; ++n)
        acc[m][n] = __builtin_amdgcn_mfma_f32_16x16x32_bf16(af[m], bfr[n], acc[m][n], 0, 0, 0);
    __syncthreads();
  }

  const int crow = brow + wr + (lane >> 4) * 4;
  const int ccol = bcol + wc + (lane & 15);
#pragma unroll
  for (int n = 0; n < 4; ++n) {
    int col = ccol + n * 16;
#pragma unroll
    for (int m = 0; m < 4; ++m)
#pragma unroll
      for (int r = 0; r < 4; ++r)
        C[(size_t)(crow + m * 16 + r) * N + col] = acc[m][n][r];
  }
}

// ---------------- GEMM 256x128, 8 waves (4M x 2N), BK=32, 2-phase dbuf -----
template<bool OUT_BF16, bool ADD_BIAS>
__global__ __launch_bounds__(512) void k_gemm_bt2(const u16* __restrict__ A,
    const u16* __restrict__ B, void* __restrict__ Cv,
    const float* __restrict__ bias, float scale, int M, int N, int K) {
  __shared__ u16 lA[2][256 * 32];   // 16KB per buf
  __shared__ u16 lB[2][128 * 32];   // 8KB per buf
  const int tid  = threadIdx.x;
  const int wid  = tid >> 6;        // 0..7
  const int lane = tid & 63;
  const int brow = blockIdx.x * 256;
  const int bcol = blockIdx.y * 128;
  const int wr = (wid >> 1) * 64;   // 4 M-groups
  const int wc = (wid & 1) * 64;    // 2 N-groups

  const int rl = lane >> 2;          // row within 16-row group
  const int ks = (lane & 3) * 8;     // 8-elem k chunk
  const u16* gA0 = A + (size_t)(brow + wid * 16 + rl) * K + ks;
  const u16* gA1 = A + (size_t)(brow + 128 + wid * 16 + rl) * K + ks;
  const u16* gB0 = B + (size_t)(bcol + wid * 16 + rl) * K + ks;

  f32x4 acc[4][4] = {};
  const int ar = lane & 15;
  const int ak = (lane >> 4) * 8;

  auto stage = [&](int k0, int buf) {
    __builtin_amdgcn_global_load_lds(GAS(gA0 + k0), LAS(&lA[buf][wid * 512]), 16, 0, 0);
    __builtin_amdgcn_global_load_lds(GAS(gA1 + k0), LAS(&lA[buf][4096 + wid * 512]), 16, 0, 0);
    __builtin_amdgcn_global_load_lds(GAS(gB0 + k0), LAS(&lB[buf][wid * 512]), 16, 0, 0);
  };

  stage(0, 0);
  __syncthreads();

  const int nk = K >> 5;
  for (int t = 0; t < nk; ++t) {
    const int buf = t & 1;
    if (t + 1 < nk) stage((t + 1) << 5, buf ^ 1);
    bf16x8 af[4], bfr[4];
#pragma unroll
    for (int m = 0; m < 4; ++m)
      af[m] = *(const bf16x8*)&lA[buf][(wr + m * 16 + ar) * 32 + ak];
#pragma unroll
    for (int n = 0; n < 4; ++n)
      bfr[n] = *(const bf16x8*)&lB[buf][(wc + n * 16 + ar) * 32 + ak];
#pragma unroll
    for (int m = 0; m < 4; ++m)
#pragma unroll
      for (int n = 0; n < 4; ++n)
        acc[m][n] = __builtin_amdgcn_mfma_f32_16x16x32_bf16(af[m], bfr[n], acc[m][n], 0, 0, 0);
    __syncthreads();
  }

  const int crow = brow + wr + (lane >> 4) * 4;
  const int ccol = bcol + wc + (lane & 15);
#pragma unroll
  for (int n = 0; n < 4; ++n) {
    int col = ccol + n * 16;
    float bv = ADD_BIAS ? bias[col] : 0.0f;
#pragma unroll
    for (int m = 0; m < 4; ++m)
#pragma unroll
      for (int r = 0; r < 4; ++r) {
        size_t idx = (size_t)(crow + m * 16 + r) * N + col;
        float val = acc[m][n][r] * scale + bv;
        if (OUT_BF16) ((u16*)Cv)[idx] = f2bf(val);
        else          ((float*)Cv)[idx] = val;
      }
  }
}

// ---------------- kv GEMM 256x128 with fused pack epilogue -----------------
// Same body as k_gemm_bt2 (M=8192, N=1024, K=512); epilogue writes straight
// into the packed K / V^T tile layouts (deletes k_pack + kvb round-trip).
__global__ __launch_bounds__(512) void k_gemm_kv(const u16* __restrict__ A,
    const u16* __restrict__ B, u16* __restrict__ kpk, u16* __restrict__ vpk) {
  const int K = 512;
  __shared__ u16 lA[2][256 * 32];
  __shared__ u16 lB[2][128 * 32];
  const int tid  = threadIdx.x;
  const int wid  = tid >> 6;
  const int lane = tid & 63;
  const int brow = blockIdx.x * 256;
  const int bcol = blockIdx.y * 128;
  const int wr = (wid >> 1) * 64;
  const int wc = (wid & 1) * 64;

  const int rl = lane >> 2;
  const int ks = (lane & 3) * 8;
  const u16* gA0 = A + (size_t)(brow + wid * 16 + rl) * K + ks;
  const u16* gA1 = A + (size_t)(brow + 128 + wid * 16 + rl) * K + ks;
  const u16* gB0 = B + (size_t)(bcol + wid * 16 + rl) * K + ks;

  f32x4 acc[4][4] = {};
  const int ar = lane & 15;
  const int ak = (lane >> 4) * 8;

  auto stage = [&](int k0, int buf) {
    __builtin_amdgcn_global_load_lds(GAS(gA0 + k0), LAS(&lA[buf][wid * 512]), 16, 0, 0);
    __builtin_amdgcn_global_load_lds(GAS(gA1 + k0), LAS(&lA[buf][4096 + wid * 512]), 16, 0, 0);
    __builtin_amdgcn_global_load_lds(GAS(gB0 + k0), LAS(&lB[buf][wid * 512]), 16, 0, 0);
  };

  stage(0, 0);
  __syncthreads();

  const int nk = K >> 5;
  for (int t = 0; t < nk; ++t) {
    const int buf = t & 1;
    if (t + 1 < nk) stage((t + 1) << 5, buf ^ 1);
    bf16x8 af[4], bfr[4];
#pragma unroll
    for (int m = 0; m < 4; ++m)
      af[m] = *(const bf16x8*)&lA[buf][(wr + m * 16 + ar) * 32 + ak];
#pragma unroll
    for (int n = 0; n < 4; ++n)
      bfr[n] = *(const bf16x8*)&lB[buf][(wc + n * 16 + ar) * 32 + ak];
#pragma unroll
    for (int m = 0; m < 4; ++m)
#pragma unroll
      for (int n = 0; n < 4; ++n)
        acc[m][n] = __builtin_amdgcn_mfma_f32_16x16x32_bf16(af[m], bfr[n], acc[m][n], 0, 0, 0);
    __syncthreads();
  }

  const int crow = brow + wr + (lane >> 4) * 4;
  const int ccol = bcol + wc + (lane & 15);
  const bool isV = (bcol >= 512);
  u16* dst = isV ? vpk : kpk;

  int colt[4];
#pragma unroll
  for (int n = 0; n < 4; ++n) {
    int col = ccol + n * 16;
    int rem = col & 511;
    int m = rem >> 6, c = rem & 63;
    colt[n] = isV ? (m * 65536 + (c >> 5) * 2048 + (c & 31) * 8)
                  : (m * 65536 + (c >> 4) * 512 + ((c >> 3) & 1) * 256 + (c & 7));
  }
#pragma unroll
  for (int mi = 0; mi < 4; ++mi)
#pragma unroll
    for (int r = 0; r < 4; ++r) {
      int row = crow + mi * 16 + r;
      int b2 = row >> 10, d = row & 1023;
      int kt = d >> 6, dl = d & 63;
      int rowt = b2 * 524288 + kt * 4096 +
                 (isV ? ((dl >> 4) * 512 + ((dl >> 3) & 1) * 256 + (dl & 7))
                      : ((dl >> 5) * 2048 + (dl & 31) * 8));
#pragma unroll
      for (int n = 0; n < 4; ++n)
        dst[rowt + colt[n]] = f2bf(acc[mi][n][r]);
    }
}

// ---------------- LayerNorm (adds sr_b first), rows of 512, wave/row -------
__global__ __launch_bounds__(256) void k_ln(const float* __restrict__ cin,
    const float* __restrict__ srb, const float* __restrict__ g,
    const float* __restrict__ bb, u16* __restrict__ out) {
  int row  = blockIdx.x * 4 + (threadIdx.x >> 6);
  int lane = threadIdx.x & 63;
  const float* src = cin + (size_t)row * 512 + lane * 8;
  float4 a  = *(const float4*)src;
  float4 b  = *(const float4*)(src + 4);
  float4 s1 = *(const float4*)(srb + lane * 8);
  float4 s2 = *(const float4*)(srb + lane * 8 + 4);
  float v[8] = { a.x + s1.x, a.y + s1.y, a.z + s1.z, a.w + s1.w,
                 b.x + s2.x, b.y + s2.y, b.z + s2.z, b.w + s2.w };
  float sum = 0.f, sq = 0.f;
#pragma unroll
  for (int i = 0; i < 8; ++i) { sum += v[i]; sq += v[i] * v[i]; }
  for (int m = 1; m < 64; m <<= 1) {
    sum += __shfl_xor(sum, m, 64);
    sq  += __shfl_xor(sq,  m, 64);
  }
  float mean = sum * (1.0f / 512.0f);
  float var  = sq * (1.0f / 512.0f) - mean * mean;
  float rstd = rsqrtf(var + 1e-5f);
  float4 g1 = *(const float4*)(g + lane * 8);
  float4 g2 = *(const float4*)(g + lane * 8 + 4);
  float4 b1 = *(const float4*)(bb + lane * 8);
  float4 b2 = *(const float4*)(bb + lane * 8 + 4);
  float gg[8] = { g1.x, g1.y, g1.z, g1.w, g2.x, g2.y, g2.z, g2.w };
  float bv[8] = { b1.x, b1.y, b1.z, b1.w, b2.x, b2.y, b2.z, b2.w };
  uint4 pk;
  u32 w0[8];
#pragma unroll
  for (int i = 0; i < 8; ++i) w0[i] = f2bf((v[i] - mean) * rstd * gg[i] + bv[i]);
  pk.x = w0[0] | (w0[1] << 16);
  pk.y = w0[2] | (w0[3] << 16);
  pk.z = w0[4] | (w0[5] << 16);
  pk.w = w0[6] | (w0[7] << 16);
  *(uint4*)(out + (size_t)row * 512 + lane * 8) = pk;
}

// ---------------- flash attention (round-15 verified best) -----------------
// Swapped 32x32, no-max softmax (p = exp2(z)); K double-buffered in LDS via
// global_load_lds; V read straight from packed global (L2-resident); row-sum
// on the MFMA pipe via ones A-operand. NO launch_bounds cap: body needs ~108
// VGPR; caps at 4 or 5 waves/SIMD collapse the allocator to 48-64 VGPR with
// catastrophic scratch spill (rounds 5 & 16).
__global__ __launch_bounds__(256) void k_attn(const u16* __restrict__ q,
    const u16* __restrict__ kpk, const u16* __restrict__ vpk,
    u16* __restrict__ out) {
  __shared__ u16 kl[2][4096];   // 8KB per buffer, K only
  const int sw   = blockIdx.x;               // 0..2047
  const int slot = sw >> 3;
  const int bm   = (sw & 7) * 8 + (slot >> 5);
  const int qx   = slot & 31;
  const int b  = bm >> 3, mm = bm & 7;
  const int wid  = threadIdx.x >> 6;
  const int lane = threadIdx.x & 63;
  const int l31  = lane & 31;
  const int hi   = lane >> 5;
  const int hi8  = hi * 8;
  const int q0   = qx * 128 + wid * 32;

  const u16* qrow = q + (size_t)(b * 4096 + q0 + l31) * 512 + mm * 64 + hi8;
  bf16x8 qf[4];
#pragma unroll
  for (int cs = 0; cs < 4; ++cs) qf[cs] = *(const bf16x8*)(qrow + cs * 16);

  const u16* kp = kpk + (size_t)bm * 65536;
  const u16* vp = vpk + (size_t)bm * 65536;
  const int loff = lane * 8;
  const int c0   = wid * 2;

  union { u32 w[4]; bf16x8 v; } onesu;
  onesu.w[0] = onesu.w[1] = onesu.w[2] = onesu.w[3] = 0x3F803F80u;
  const bf16x8 ones = onesu.v;

  f32x16 o0 = {}, o1 = {}, o2 = {};

  auto stage = [&](int t, int buf) {
    const u16* ks = kp + t * 4096 + c0 * 512 + loff;
    __builtin_amdgcn_global_load_lds(GAS(ks),       LAS(&kl[buf][c0 * 512]),       16, 0, 0);
    __builtin_amdgcn_global_load_lds(GAS(ks + 512), LAS(&kl[buf][c0 * 512 + 512]), 16, 0, 0);
  };

  auto body = [&](int t, int buf) {
    if (t + 1 < 16) stage(t + 1, buf ^ 1);

    const u16* vt = vp + t * 4096 + loff;
    bf16x8 vf[8];
#pragma unroll
    for (int i = 0; i < 8; ++i) vf[i] = *(const bf16x8*)(vt + i * 512);

    bf16x8 kf[8];
#pragma unroll
    for (int i = 0; i < 8; ++i)
      kf[i] = *(const bf16x8*)&kl[buf][i * 512 + loff];

    f32x16 s0 = {}, s1 = {};
    __builtin_amdgcn_s_setprio(1);
#pragma unroll
    for (int cs = 0; cs < 4; ++cs) {
      s0 = __builtin_amdgcn_mfma_f32_32x32x16_bf16(kf[cs],     qf[cs], s0, 0, 0, 0);
      s1 = __builtin_amdgcn_mfma_f32_32x32x16_bf16(kf[4 + cs], qf[cs], s1, 0, 0, 0);
    }
    __builtin_amdgcn_s_setprio(0);

    float pr[2][16];
#pragma unroll
    for (int i = 0; i < 16; ++i) {
      pr[0][i] = __builtin_amdgcn_exp2f(s0[i]);
      pr[1][i] = __builtin_amdgcn_exp2f(s1[i]);
    }

    bf16x8 pa[4];
#pragma unroll
    for (int half = 0; half < 2; ++half)
#pragma unroll
      for (int ks = 0; ks < 2; ++ks) {
        u32 wa = cvtpk(pr[half][ks * 8 + 0], pr[half][ks * 8 + 1]);
        u32 wb = cvtpk(pr[half][ks * 8 + 4], pr[half][ks * 8 + 5]);
        u32 wc = cvtpk(pr[half][ks * 8 + 2], pr[half][ks * 8 + 3]);
        u32 wd = cvtpk(pr[half][ks * 8 + 6], pr[half][ks * 8 + 7]);
        perm32swap(wa, wb);
        perm32swap(wc, wd);
        union { u32 w[4]; bf16x8 v; } uu;
        uu.w[0] = wa; uu.w[1] = wc; uu.w[2] = wb; uu.w[3] = wd;
        pa[half * 2 + ks] = uu.v;
      }

    __builtin_amdgcn_s_setprio(1);
#pragma unroll
    for (int ks = 0; ks < 4; ++ks) {
      o0 = __builtin_amdgcn_mfma_f32_32x32x16_bf16(vf[ks],     pa[ks], o0, 0, 0, 0);
      o1 = __builtin_amdgcn_mfma_f32_32x32x16_bf16(vf[4 + ks], pa[ks], o1, 0, 0, 0);
      o2 = __builtin_amdgcn_mfma_f32_32x32x16_bf16(ones,       pa[ks], o2, 0, 0, 0);
    }
    __builtin_amdgcn_s_setprio(0);
    __syncthreads();
  };

  stage(0, 0);
  __syncthreads();
  for (int t = 0; t < 16; t += 2) {
    body(t, 0);
    body(t + 1, 1);
  }

  float inv = 1.0f / o2[0];
  u16* obase = out + (size_t)(b * 4096 + q0 + l31) * 512 + mm * 64 + hi * 4;
#pragma unroll
  for (int ct = 0; ct < 2; ++ct)
#pragma unroll
    for (int g = 0; g < 4; ++g) {
      ushort4 st;
      st.x = f2bf((ct ? o1[g * 4 + 0] : o0[g * 4 + 0]) * inv);
      st.y = f2bf((ct ? o1[g * 4 + 1] : o0[g * 4 + 1]) * inv);
      st.z = f2bf((ct ? o1[g * 4 + 2] : o0[g * 4 + 2]) * inv);
      st.w = f2bf((ct ? o1[g * 4 + 3] : o0[g * 4 + 3]) * inv);
      *(ushort4*)(obase + ct * 32 + g * 8) = st;
    }
}

// ---------------------------------------------------------------------------
extern "C" void kernel_launch(void* const* d_in, const int* in_sizes, int n_in,
                              void* d_out, int out_size, void* d_ws, size_t ws_size,
                              hipStream_t stream) {
  const float* x      = (const float*)d_in[0];
  const float* q_w    = (const float*)d_in[3];
  const float* kv_w   = (const float*)d_in[4];
  const float* proj_w = (const float*)d_in[5];
  const float* proj_b = (const float*)d_in[6];
  const float* sr_w   = (const float*)d_in[7];
  const float* sr_b   = (const float*)d_in[8];
  const float* ng     = (const float*)d_in[9];
  const float* nb     = (const float*)d_in[10];

  char* ws = (char*)d_ws;
  size_t off = 0;
  auto alloc = [&](size_t bytes) {
    char* p = ws + off;
    off += (bytes + 255) & ~(size_t)255;
    return p;
  };
  u16* wq      = (u16*)alloc(512 * 512 * 2);
  u16* wkv     = (u16*)alloc(1024 * 512 * 2);
  u16* wpr     = (u16*)alloc(512 * 512 * 2);
  u16* wsr     = (u16*)alloc(512 * 2048 * 2);
  u16* xb      = (u16*)alloc(33554432);      // [32768,512] bf16
  u16* qbuf    = (u16*)alloc(33554432);      // [32768,512] bf16 (pre-scaled)
  u16* xsln    = (u16*)alloc(8388608);       // [8192,512]  bf16
  u16* kpkb    = (u16*)alloc(8388608);       // packed K tiles
  u16* vpkb    = (u16*)alloc(8388608);       // packed V^T tiles
  float* convout = (float*)alloc(16777216);  // [8192,512] f32
  u16* attn_o  = xb;                         // alias: xb dead after conv GEMM

  const float zsc = 0.125f * 1.44269504f;    // SCALE * log2(e)

  k_cast_x<<<8192, 256, 0, stream>>>(x, xb);
  k_cast_w<<<8192, 256, 0, stream>>>(q_w, kv_w, proj_w, sr_w, wq, wkv, wpr, wsr);
  k_gemm_bt2<true,  false><<<dim3(128, 4), 512, 0, stream>>>(xb, wq, qbuf, nullptr, zsc, 32768, 512, 512);
  k_gemm_conv<<<dim3(64, 4), 256, 0, stream>>>(xb, wsr, convout, 512, 2048);
  k_ln<<<2048, 256, 0, stream>>>(convout, sr_b, ng, nb, xsln);
  k_gemm_kv<<<dim3(32, 8), 512, 0, stream>>>(xsln, wkv, kpkb, vpkb);
  k_attn<<<2048, 256, 0, stream>>>(qbuf, kpkb, vpkb, attn_o);
  k_gemm_bt2<false, true><<<dim3(128, 4), 512, 0, stream>>>(attn_o, wpr, (float*)d_out, proj_b, 1.0f, 32768, 512, 512);
}

// Round 18
// 230.862 us; speedup vs baseline: 4.1367x; 1.0371x over previous
//
#include <hip/hip_runtime.h>
#include <stdint.h>

typedef unsigned short u16;
typedef unsigned int   u32;

using bf16x8 = __attribute__((ext_vector_type(8))) __bf16;
using f32x4  = __attribute__((ext_vector_type(4))) float;
using f32x16 = __attribute__((ext_vector_type(16))) float;

#define GAS(p) ((const __attribute__((address_space(1))) void*)(p))
#define LAS(p) ((__attribute__((address_space(3))) void*)(p))

__device__ __forceinline__ u16 f2bf(float f) {
  union { float f; u32 u; } v; v.f = f;
  return (u16)((v.u + 0x7FFFu + ((v.u >> 16) & 1u)) >> 16);
}

__device__ __forceinline__ u32 cvtpk(float lo, float hi) {
  u32 r;
  asm("v_cvt_pk_bf16_f32 %0, %1, %2" : "=v"(r) : "v"(lo), "v"(hi));
  return r;
}

// vdst lanes [32:63] <-> vsrc lanes [0:31].  Only call with DISTINCT values
// (identical values get register-coalesced -> self-swap bug).
__device__ __forceinline__ void perm32swap(u32& a, u32& b) {
  asm volatile("v_permlane32_swap_b32 %0, %1" : "+v"(a), "+v"(b));
}

// ---------------- merged cast: x -> bf16 AND weights -> bf16 ---------------
// blocks [0,8192): x cast; blocks [8192,16384): weight cast (+sr_w repack).
// Merging removes one kernel launch+drain (no data dependence between them).
__global__ __launch_bounds__(256) void k_cast(const float* __restrict__ x,
    u16* __restrict__ xb, const float* __restrict__ qw,
    const float* __restrict__ kvw, const float* __restrict__ pw,
    const float* __restrict__ srw, u16* __restrict__ oqw, u16* __restrict__ okvw,
    u16* __restrict__ opw, u16* __restrict__ osrw) {
  const int bid = blockIdx.x;
  if (bid < 8192) {
    int t   = bid * 256 + threadIdx.x;        // 2,097,152 total
    int row = t >> 6;
    int seg = t & 63;
    const float* src = x + (size_t)row * 512 + seg * 8;
    float4 a = *(const float4*)src;
    float4 b = *(const float4*)(src + 4);
    uint4 pk;
    pk.x = (u32)f2bf(a.x) | ((u32)f2bf(a.y) << 16);
    pk.y = (u32)f2bf(a.z) | ((u32)f2bf(a.w) << 16);
    pk.z = (u32)f2bf(b.x) | ((u32)f2bf(b.y) << 16);
    pk.w = (u32)f2bf(b.z) | ((u32)f2bf(b.w) << 16);
    *(uint4*)(xb + (size_t)row * 512 + seg * 8) = pk;
  } else {
    int t = (bid - 8192) * 256 + threadIdx.x; // 2,097,152 total
    if (t < 262144) {
      oqw[t] = f2bf(qw[t]);
    } else if (t < 786432) {
      int i = t - 262144; okvw[i] = f2bf(kvw[i]);
    } else if (t < 1048576) {
      int i = t - 786432; opw[i] = f2bf(pw[i]);
    } else {
      int i = t - 1048576;            // dst index: o*2048 + kk*512 + ic
      int o  = i >> 11;
      int r  = i & 2047;
      int kk = r >> 9;                // ky*2+kx
      int ic = r & 511;
      int ky = kk >> 1, kx = kk & 1;
      osrw[i] = f2bf(srw[(((size_t)o * 512 + ic) * 2 + ky) * 2 + kx]);
    }
  }
}

// ---------------- conv GEMM 64x128 tile, A gathered straight from xb -------
// 512 blocks (2/CU, 2 waves/SIMD) instead of the old 128x128's 256 (1/CU):
// K=2048 has 64 barrier-drained steps; TLP across 2 resident blocks hides
// the per-step stall that 1 wave/SIMD fully exposed.
// Patch row r: b=r>>10, py=(r&1023)>>5, px=r&31; kk/ic part of the patch
// column is a UNIFORM offset off(k0) (see abase/off derivation, round 11).
__global__ __launch_bounds__(256) void k_gemm_conv(const u16* __restrict__ xb,
    const u16* __restrict__ B, float* __restrict__ C, int N, int K) {
  __shared__ u16 lA[2][64 * 32];    // 4KB per buf
  __shared__ u16 lB[2][128 * 32];   // 8KB per buf
  const int tid  = threadIdx.x;
  const int wid  = tid >> 6;
  const int lane = tid & 63;
  const int brow = blockIdx.x * 64;
  const int bcol = blockIdx.y * 128;
  const int wr = (wid >> 1) * 32;   // 0 or 32
  const int wc = (wid & 1) * 64;    // 0 or 64

  const int rl = lane >> 2;
  const int ks = (lane & 3) * 8;
  auto abase = [&](int r) {
    int b2 = r >> 10, pr = r & 1023;
    return xb + ((size_t)b2 * 4096 + (pr >> 5) * 128 + (pr & 31) * 2) * 512 + ks;
  };
  const u16* gA0 = abase(brow + wid * 16 + rl);           // A chunk = wid
  const u16* gB0 = B + (size_t)(bcol + (wid * 2 + 0) * 16 + rl) * K + ks;
  const u16* gB1 = B + (size_t)(bcol + (wid * 2 + 1) * 16 + rl) * K + ks;

  f32x4 acc[2][4] = {};
  const int ar = lane & 15;
  const int ak = (lane >> 4) * 8;

  auto stage = [&](int k0, int buf) {
    int off = ((k0 >> 10) & 1) * 32768 + ((k0 >> 9) & 1) * 512 + (k0 & 511);
    __builtin_amdgcn_global_load_lds(GAS(gA0 + off), LAS(&lA[buf][wid * 512]), 16, 0, 0);
    __builtin_amdgcn_global_load_lds(GAS(gB0 + k0),  LAS(&lB[buf][(wid * 2 + 0) * 512]), 16, 0, 0);
    __builtin_amdgcn_global_load_lds(GAS(gB1 + k0),  LAS(&lB[buf][(wid * 2 + 1) * 512]), 16, 0, 0);
  };

  stage(0, 0);
  __syncthreads();

  const int nk = K >> 5;
  for (int t = 0; t < nk; ++t) {
    const int buf = t & 1;
    if (t + 1 < nk) stage((t + 1) << 5, buf ^ 1);
    bf16x8 af[2], bfr[4];
#pragma unroll
    for (int m = 0; m < 2; ++m)
      af[m] = *(const bf16x8*)&lA[buf][(wr + m * 16 + ar) * 32 + ak];
#pragma unroll
    for (int n = 0; n < 4; ++n)
      bfr[n] = *(const bf16x8*)&lB[buf][(wc + n * 16 + ar) * 32 + ak];
#pragma unroll
    for (int m = 0; m < 2; ++m)
#pragma unroll
      for (int n = 0; n < 4; ++n)
        acc[m][n] = __builtin_amdgcn_mfma_f32_16x16x32_bf16(af[m], bfr[n], acc[m][n], 0, 0, 0);
    __syncthreads();
  }

  const int crow = brow + wr + (lane >> 4) * 4;
  const int ccol = bcol + wc + (lane & 15);
#pragma unroll
  for (int n = 0; n < 4; ++n) {
    int col = ccol + n * 16;
#pragma unroll
    for (int m = 0; m < 2; ++m)
#pragma unroll
      for (int r = 0; r < 4; ++r)
        C[(size_t)(crow + m * 16 + r) * N + col] = acc[m][n][r];
  }
}

// ---------------- GEMM 256x128, 8 waves (4M x 2N), BK=32, 2-phase dbuf -----
template<bool OUT_BF16, bool ADD_BIAS>
__global__ __launch_bounds__(512) void k_gemm_bt2(const u16* __restrict__ A,
    const u16* __restrict__ B, void* __restrict__ Cv,
    const float* __restrict__ bias, float scale, int M, int N, int K) {
  __shared__ u16 lA[2][256 * 32];   // 16KB per buf
  __shared__ u16 lB[2][128 * 32];   // 8KB per buf
  const int tid  = threadIdx.x;
  const int wid  = tid >> 6;        // 0..7
  const int lane = tid & 63;
  const int brow = blockIdx.x * 256;
  const int bcol = blockIdx.y * 128;
  const int wr = (wid >> 1) * 64;   // 4 M-groups
  const int wc = (wid & 1) * 64;    // 2 N-groups

  const int rl = lane >> 2;          // row within 16-row group
  const int ks = (lane & 3) * 8;     // 8-elem k chunk
  const u16* gA0 = A + (size_t)(brow + wid * 16 + rl) * K + ks;
  const u16* gA1 = A + (size_t)(brow + 128 + wid * 16 + rl) * K + ks;
  const u16* gB0 = B + (size_t)(bcol + wid * 16 + rl) * K + ks;

  f32x4 acc[4][4] = {};
  const int ar = lane & 15;
  const int ak = (lane >> 4) * 8;

  auto stage = [&](int k0, int buf) {
    __builtin_amdgcn_global_load_lds(GAS(gA0 + k0), LAS(&lA[buf][wid * 512]), 16, 0, 0);
    __builtin_amdgcn_global_load_lds(GAS(gA1 + k0), LAS(&lA[buf][4096 + wid * 512]), 16, 0, 0);
    __builtin_amdgcn_global_load_lds(GAS(gB0 + k0), LAS(&lB[buf][wid * 512]), 16, 0, 0);
  };

  stage(0, 0);
  __syncthreads();

  const int nk = K >> 5;
  for (int t = 0; t < nk; ++t) {
    const int buf = t & 1;
    if (t + 1 < nk) stage((t + 1) << 5, buf ^ 1);
    bf16x8 af[4], bfr[4];
#pragma unroll
    for (int m = 0; m < 4; ++m)
      af[m] = *(const bf16x8*)&lA[buf][(wr + m * 16 + ar) * 32 + ak];
#pragma unroll
    for (int n = 0; n < 4; ++n)
      bfr[n] = *(const bf16x8*)&lB[buf][(wc + n * 16 + ar) * 32 + ak];
#pragma unroll
    for (int m = 0; m < 4; ++m)
#pragma unroll
      for (int n = 0; n < 4; ++n)
        acc[m][n] = __builtin_amdgcn_mfma_f32_16x16x32_bf16(af[m], bfr[n], acc[m][n], 0, 0, 0);
    __syncthreads();
  }

  const int crow = brow + wr + (lane >> 4) * 4;
  const int ccol = bcol + wc + (lane & 15);
#pragma unroll
  for (int n = 0; n < 4; ++n) {
    int col = ccol + n * 16;
    float bv = ADD_BIAS ? bias[col] : 0.0f;
#pragma unroll
    for (int m = 0; m < 4; ++m)
#pragma unroll
      for (int r = 0; r < 4; ++r) {
        size_t idx = (size_t)(crow + m * 16 + r) * N + col;
        float val = acc[m][n][r] * scale + bv;
        if (OUT_BF16) ((u16*)Cv)[idx] = f2bf(val);
        else          ((float*)Cv)[idx] = val;
      }
  }
}

// ---------------- kv GEMM 256x128 with fused pack epilogue -----------------
// Same body as k_gemm_bt2 (M=8192, N=1024, K=512); epilogue writes straight
// into the packed K / V^T tile layouts (deletes k_pack + kvb round-trip).
__global__ __launch_bounds__(512) void k_gemm_kv(const u16* __restrict__ A,
    const u16* __restrict__ B, u16* __restrict__ kpk, u16* __restrict__ vpk) {
  const int K = 512;
  __shared__ u16 lA[2][256 * 32];
  __shared__ u16 lB[2][128 * 32];
  const int tid  = threadIdx.x;
  const int wid  = tid >> 6;
  const int lane = tid & 63;
  const int brow = blockIdx.x * 256;
  const int bcol = blockIdx.y * 128;
  const int wr = (wid >> 1) * 64;
  const int wc = (wid & 1) * 64;

  const int rl = lane >> 2;
  const int ks = (lane & 3) * 8;
  const u16* gA0 = A + (size_t)(brow + wid * 16 + rl) * K + ks;
  const u16* gA1 = A + (size_t)(brow + 128 + wid * 16 + rl) * K + ks;
  const u16* gB0 = B + (size_t)(bcol + wid * 16 + rl) * K + ks;

  f32x4 acc[4][4] = {};
  const int ar = lane & 15;
  const int ak = (lane >> 4) * 8;

  auto stage = [&](int k0, int buf) {
    __builtin_amdgcn_global_load_lds(GAS(gA0 + k0), LAS(&lA[buf][wid * 512]), 16, 0, 0);
    __builtin_amdgcn_global_load_lds(GAS(gA1 + k0), LAS(&lA[buf][4096 + wid * 512]), 16, 0, 0);
    __builtin_amdgcn_global_load_lds(GAS(gB0 + k0), LAS(&lB[buf][wid * 512]), 16, 0, 0);
  };

  stage(0, 0);
  __syncthreads();

  const int nk = K >> 5;
  for (int t = 0; t < nk; ++t) {
    const int buf = t & 1;
    if (t + 1 < nk) stage((t + 1) << 5, buf ^ 1);
    bf16x8 af[4], bfr[4];
#pragma unroll
    for (int m = 0; m < 4; ++m)
      af[m] = *(const bf16x8*)&lA[buf][(wr + m * 16 + ar) * 32 + ak];
#pragma unroll
    for (int n = 0; n < 4; ++n)
      bfr[n] = *(const bf16x8*)&lB[buf][(wc + n * 16 + ar) * 32 + ak];
#pragma unroll
    for (int m = 0; m < 4; ++m)
#pragma unroll
      for (int n = 0; n < 4; ++n)
        acc[m][n] = __builtin_amdgcn_mfma_f32_16x16x32_bf16(af[m], bfr[n], acc[m][n], 0, 0, 0);
    __syncthreads();
  }

  const int crow = brow + wr + (lane >> 4) * 4;
  const int ccol = bcol + wc + (lane & 15);
  const bool isV = (bcol >= 512);
  u16* dst = isV ? vpk : kpk;

  int colt[4];
#pragma unroll
  for (int n = 0; n < 4; ++n) {
    int col = ccol + n * 16;
    int rem = col & 511;
    int m = rem >> 6, c = rem & 63;
    colt[n] = isV ? (m * 65536 + (c >> 5) * 2048 + (c & 31) * 8)
                  : (m * 65536 + (c >> 4) * 512 + ((c >> 3) & 1) * 256 + (c & 7));
  }
#pragma unroll
  for (int mi = 0; mi < 4; ++mi)
#pragma unroll
    for (int r = 0; r < 4; ++r) {
      int row = crow + mi * 16 + r;
      int b2 = row >> 10, d = row & 1023;
      int kt = d >> 6, dl = d & 63;
      int rowt = b2 * 524288 + kt * 4096 +
                 (isV ? ((dl >> 4) * 512 + ((dl >> 3) & 1) * 256 + (dl & 7))
                      : ((dl >> 5) * 2048 + (dl & 31) * 8));
#pragma unroll
      for (int n = 0; n < 4; ++n)
        dst[rowt + colt[n]] = f2bf(acc[mi][n][r]);
    }
}

// ---------------- LayerNorm (adds sr_b first), rows of 512, wave/row -------
__global__ __launch_bounds__(256) void k_ln(const float* __restrict__ cin,
    const float* __restrict__ srb, const float* __restrict__ g,
    const float* __restrict__ bb, u16* __restrict__ out) {
  int row  = blockIdx.x * 4 + (threadIdx.x >> 6);
  int lane = threadIdx.x & 63;
  const float* src = cin + (size_t)row * 512 + lane * 8;
  float4 a  = *(const float4*)src;
  float4 b  = *(const float4*)(src + 4);
  float4 s1 = *(const float4*)(srb + lane * 8);
  float4 s2 = *(const float4*)(srb + lane * 8 + 4);
  float v[8] = { a.x + s1.x, a.y + s1.y, a.z + s1.z, a.w + s1.w,
                 b.x + s2.x, b.y + s2.y, b.z + s2.z, b.w + s2.w };
  float sum = 0.f, sq = 0.f;
#pragma unroll
  for (int i = 0; i < 8; ++i) { sum += v[i]; sq += v[i] * v[i]; }
  for (int m = 1; m < 64; m <<= 1) {
    sum += __shfl_xor(sum, m, 64);
    sq  += __shfl_xor(sq,  m, 64);
  }
  float mean = sum * (1.0f / 512.0f);
  float var  = sq * (1.0f / 512.0f) - mean * mean;
  float rstd = rsqrtf(var + 1e-5f);
  float4 g1 = *(const float4*)(g + lane * 8);
  float4 g2 = *(const float4*)(g + lane * 8 + 4);
  float4 b1 = *(const float4*)(bb + lane * 8);
  float4 b2 = *(const float4*)(bb + lane * 8 + 4);
  float gg[8] = { g1.x, g1.y, g1.z, g1.w, g2.x, g2.y, g2.z, g2.w };
  float bv[8] = { b1.x, b1.y, b1.z, b1.w, b2.x, b2.y, b2.z, b2.w };
  uint4 pk;
  u32 w0[8];
#pragma unroll
  for (int i = 0; i < 8; ++i) w0[i] = f2bf((v[i] - mean) * rstd * gg[i] + bv[i]);
  pk.x = w0[0] | (w0[1] << 16);
  pk.y = w0[2] | (w0[3] << 16);
  pk.z = w0[4] | (w0[5] << 16);
  pk.w = w0[6] | (w0[7] << 16);
  *(uint4*)(out + (size_t)row * 512 + lane * 8) = pk;
}

// ---------------- flash attention (round-15 verified best) -----------------
// Swapped 32x32, no-max softmax (p = exp2(z)); K double-buffered in LDS via
// global_load_lds; V read straight from packed global (L2-resident); row-sum
// on the MFMA pipe via ones A-operand. NO launch_bounds cap: body needs ~108
// VGPR; caps at 4 or 5 waves/SIMD collapse the allocator to 48-64 VGPR with
// catastrophic scratch spill (rounds 5 & 16).
__global__ __launch_bounds__(256) void k_attn(const u16* __restrict__ q,
    const u16* __restrict__ kpk, const u16* __restrict__ vpk,
    u16* __restrict__ out) {
  __shared__ u16 kl[2][4096];   // 8KB per buffer, K only
  const int sw   = blockIdx.x;               // 0..2047
  const int slot = sw >> 3;
  const int bm   = (sw & 7) * 8 + (slot >> 5);
  const int qx   = slot & 31;
  const int b  = bm >> 3, mm = bm & 7;
  const int wid  = threadIdx.x >> 6;
  const int lane = threadIdx.x & 63;
  const int l31  = lane & 31;
  const int hi   = lane >> 5;
  const int hi8  = hi * 8;
  const int q0   = qx * 128 + wid * 32;

  const u16* qrow = q + (size_t)(b * 4096 + q0 + l31) * 512 + mm * 64 + hi8;
  bf16x8 qf[4];
#pragma unroll
  for (int cs = 0; cs < 4; ++cs) qf[cs] = *(const bf16x8*)(qrow + cs * 16);

  const u16* kp = kpk + (size_t)bm * 65536;
  const u16* vp = vpk + (size_t)bm * 65536;
  const int loff = lane * 8;
  const int c0   = wid * 2;

  union { u32 w[4]; bf16x8 v; } onesu;
  onesu.w[0] = onesu.w[1] = onesu.w[2] = onesu.w[3] = 0x3F803F80u;
  const bf16x8 ones = onesu.v;

  f32x16 o0 = {}, o1 = {}, o2 = {};

  auto stage = [&](int t, int buf) {
    const u16* ks = kp + t * 4096 + c0 * 512 + loff;
    __builtin_amdgcn_global_load_lds(GAS(ks),       LAS(&kl[buf][c0 * 512]),       16, 0, 0);
    __builtin_amdgcn_global_load_lds(GAS(ks + 512), LAS(&kl[buf][c0 * 512 + 512]), 16, 0, 0);
  };

  auto body = [&](int t, int buf) {
    if (t + 1 < 16) stage(t + 1, buf ^ 1);

    const u16* vt = vp + t * 4096 + loff;
    bf16x8 vf[8];
#pragma unroll
    for (int i = 0; i < 8; ++i) vf[i] = *(const bf16x8*)(vt + i * 512);

    bf16x8 kf[8];
#pragma unroll
    for (int i = 0; i < 8; ++i)
      kf[i] = *(const bf16x8*)&kl[buf][i * 512 + loff];

    f32x16 s0 = {}, s1 = {};
    __builtin_amdgcn_s_setprio(1);
#pragma unroll
    for (int cs = 0; cs < 4; ++cs) {
      s0 = __builtin_amdgcn_mfma_f32_32x32x16_bf16(kf[cs],     qf[cs], s0, 0, 0, 0);
      s1 = __builtin_amdgcn_mfma_f32_32x32x16_bf16(kf[4 + cs], qf[cs], s1, 0, 0, 0);
    }
    __builtin_amdgcn_s_setprio(0);

    float pr[2][16];
#pragma unroll
    for (int i = 0; i < 16; ++i) {
      pr[0][i] = __builtin_amdgcn_exp2f(s0[i]);
      pr[1][i] = __builtin_amdgcn_exp2f(s1[i]);
    }

    bf16x8 pa[4];
#pragma unroll
    for (int half = 0; half < 2; ++half)
#pragma unroll
      for (int ks = 0; ks < 2; ++ks) {
        u32 wa = cvtpk(pr[half][ks * 8 + 0], pr[half][ks * 8 + 1]);
        u32 wb = cvtpk(pr[half][ks * 8 + 4], pr[half][ks * 8 + 5]);
        u32 wc = cvtpk(pr[half][ks * 8 + 2], pr[half][ks * 8 + 3]);
        u32 wd = cvtpk(pr[half][ks * 8 + 6], pr[half][ks * 8 + 7]);
        perm32swap(wa, wb);
        perm32swap(wc, wd);
        union { u32 w[4]; bf16x8 v; } uu;
        uu.w[0] = wa; uu.w[1] = wc; uu.w[2] = wb; uu.w[3] = wd;
        pa[half * 2 + ks] = uu.v;
      }

    __builtin_amdgcn_s_setprio(1);
#pragma unroll
    for (int ks = 0; ks < 4; ++ks) {
      o0 = __builtin_amdgcn_mfma_f32_32x32x16_bf16(vf[ks],     pa[ks], o0, 0, 0, 0);
      o1 = __builtin_amdgcn_mfma_f32_32x32x16_bf16(vf[4 + ks], pa[ks], o1, 0, 0, 0);
      o2 = __builtin_amdgcn_mfma_f32_32x32x16_bf16(ones,       pa[ks], o2, 0, 0, 0);
    }
    __builtin_amdgcn_s_setprio(0);
    __syncthreads();
  };

  stage(0, 0);
  __syncthreads();
  for (int t = 0; t < 16; t += 2) {
    body(t, 0);
    body(t + 1, 1);
  }

  float inv = 1.0f / o2[0];
  u16* obase = out + (size_t)(b * 4096 + q0 + l31) * 512 + mm * 64 + hi * 4;
#pragma unroll
  for (int ct = 0; ct < 2; ++ct)
#pragma unroll
    for (int g = 0; g < 4; ++g) {
      ushort4 st;
      st.x = f2bf((ct ? o1[g * 4 + 0] : o0[g * 4 + 0]) * inv);
      st.y = f2bf((ct ? o1[g * 4 + 1] : o0[g * 4 + 1]) * inv);
      st.z = f2bf((ct ? o1[g * 4 + 2] : o0[g * 4 + 2]) * inv);
      st.w = f2bf((ct ? o1[g * 4 + 3] : o0[g * 4 + 3]) * inv);
      *(ushort4*)(obase + ct * 32 + g * 8) = st;
    }
}

// ---------------------------------------------------------------------------
extern "C" void kernel_launch(void* const* d_in, const int* in_sizes, int n_in,
                              void* d_out, int out_size, void* d_ws, size_t ws_size,
                              hipStream_t stream) {
  const float* x      = (const float*)d_in[0];
  const float* q_w    = (const float*)d_in[3];
  const float* kv_w   = (const float*)d_in[4];
  const float* proj_w = (const float*)d_in[5];
  const float* proj_b = (const float*)d_in[6];
  const float* sr_w   = (const float*)d_in[7];
  const float* sr_b   = (const float*)d_in[8];
  const float* ng     = (const float*)d_in[9];
  const float* nb     = (const float*)d_in[10];

  char* ws = (char*)d_ws;
  size_t off = 0;
  auto alloc = [&](size_t bytes) {
    char* p = ws + off;
    off += (bytes + 255) & ~(size_t)255;
    return p;
  };
  u16* wq      = (u16*)alloc(512 * 512 * 2);
  u16* wkv     = (u16*)alloc(1024 * 512 * 2);
  u16* wpr     = (u16*)alloc(512 * 512 * 2);
  u16* wsr     = (u16*)alloc(512 * 2048 * 2);
  u16* xb      = (u16*)alloc(33554432);      // [32768,512] bf16
  u16* qbuf    = (u16*)alloc(33554432);      // [32768,512] bf16 (pre-scaled)
  u16* xsln    = (u16*)alloc(8388608);       // [8192,512]  bf16
  u16* kpkb    = (u16*)alloc(8388608);       // packed K tiles
  u16* vpkb    = (u16*)alloc(8388608);       // packed V^T tiles
  float* convout = (float*)alloc(16777216);  // [8192,512] f32
  u16* attn_o  = xb;                         // alias: xb dead after conv GEMM

  const float zsc = 0.125f * 1.44269504f;    // SCALE * log2(e)

  k_cast<<<16384, 256, 0, stream>>>(x, xb, q_w, kv_w, proj_w, sr_w, wq, wkv, wpr, wsr);
  k_gemm_bt2<true,  false><<<dim3(128, 4), 512, 0, stream>>>(xb, wq, qbuf, nullptr, zsc, 32768, 512, 512);
  k_gemm_conv<<<dim3(128, 4), 256, 0, stream>>>(xb, wsr, convout, 512, 2048);
  k_ln<<<2048, 256, 0, stream>>>(convout, sr_b, ng, nb, xsln);
  k_gemm_kv<<<dim3(32, 8), 512, 0, stream>>>(xsln, wkv, kpkb, vpkb);
  k_attn<<<2048, 256, 0, stream>>>(qbuf, kpkb, vpkb, attn_o);
  k_gemm_bt2<false, true><<<dim3(128, 4), 512, 0, stream>>>(attn_o, wpr, (float*)d_out, proj_b, 1.0f, 32768, 512, 512);
}